// Round 6
// baseline (1095.241 us; speedup 1.0000x reference)
//
#include <hip/hip_runtime.h>
#include <hip/hip_fp16.h>

#define B_ 512
#define T_ 512
#define H_ 64
#define K_ 4

// ---- workspace layout (shared prefix, both paths) ----
//   wht  f16 [K*3][8][64][8]  @ 0        (98304 B)  chunk-transposed W_h
//   wit  f16 [3][8][64][8]    @ 98304    (24576 B)  chunk-transposed W_i
//   flag int                  @ 123136
// fallback path:
//   xh16 f16 [B*T*H]          @ 131072   (33554432 B)
// fast path:
//   iproj f32 [B*T][3][64]    @ 131072   (201326592 B)
//   hh    f16 [B*T][64]       @ 201457664 (33554432 B)
#define WS_WIT_OFF   98304
#define WS_FLAG_OFF  123136
#define WS_XH_OFF    131072
#define WS_IPJ_OFF   131072
#define WS_HH_OFF    201457664ULL
#define WS_NEED_FAST 235012096ULL

// fallback LDS (gru_seq6): Wh [0,98304) ; Wi [98304,122880) ; h scratch @122880
#define LDS_HSC_OFF  122880
#define LDS_TOTAL    123392
#define STAGE_U4     7680

// fast-path LDS (gru_seq11): Wh [0,98304) ; h scratch @98304
//   h scratch: [chain:2][buf:2][64 halves] = 512 B
#define LDS11_HSC_OFF 98304
#define LDS11_TOTAL   98816
#define STAGE11_U4    6144

typedef _Float16 half2_t __attribute__((ext_vector_type(2)));

union Q { uint4 u; half2_t h[4]; };  // 16 B = 4 packed half2

__device__ __forceinline__ float fdot2f(half2_t a, half2_t b, float c) {
#if __has_builtin(__builtin_amdgcn_fdot2)
    return __builtin_amdgcn_fdot2(a, b, c, false);
#else
    return fmaf((float)a[0], (float)b[0], fmaf((float)a[1], (float)b[1], c));
#endif
}

__device__ __forceinline__ half2_t pkh2(float a, float b) {
    return __builtin_bit_cast(half2_t, __builtin_amdgcn_cvt_pkrtz(a, b));
}

// Detect whether mask buffer is 1-byte bools or int32 0/1 (little-endian).
__global__ void detect_mask_kernel(const unsigned char* __restrict__ mb, int* __restrict__ flag) {
    __shared__ int cnt;
    if (threadIdx.x == 0) cnt = 0;
    __syncthreads();
    int c = 0;
    for (int i = threadIdx.x; i < 4096; i += blockDim.x)
        if ((i & 3) != 0 && mb[i] != 0) c++;
    atomicAdd(&cnt, c);
    __syncthreads();
    if (threadIdx.x == 0) *flag = (cnt > 0) ? 1 : 0;  // 1 => uint8 bools, 0 => int32
}

// Weights -> f16 chunk-transposed: dst u4 index (mat*8 + j/8)*64 + i
__global__ void convert_weights_kernel(const float* __restrict__ Whr, const float* __restrict__ Whz,
                                       const float* __restrict__ Whn, const float* __restrict__ Wir,
                                       const float* __restrict__ Wiz, const float* __restrict__ Win,
                                       __half* __restrict__ wht, __half* __restrict__ wit) {
    int idx = blockIdx.x * 256 + threadIdx.x;
    if (idx < K_ * 3 * H_ * H_) {
        int mat = idx >> 12;            // k*3+g
        int i   = (idx >> 6) & 63;
        int j   = idx & 63;
        int k   = mat / 3, g = mat - 3 * k;
        const float* src = (g == 0) ? Whr : (g == 1) ? Whz : Whn;
        wht[((mat * 8 + (j >> 3)) * 64 + i) * 8 + (j & 7)] = __float2half(src[(k * H_ + i) * H_ + j]);
    }
    if (idx < 3 * H_ * H_) {
        int g = idx >> 12;
        int i = (idx >> 6) & 63;
        int j = idx & 63;
        const float* src = (g == 0) ? Wir : (g == 1) ? Wiz : Win;
        wit[((g * 8 + (j >> 3)) * 64 + i) * 8 + (j & 7)] = __float2half(src[i * H_ + j]);
    }
}

// x f32 -> packed f16 (fallback path only)
__global__ void convert_x_kernel(const float* __restrict__ xf, __half* __restrict__ xh) {
    size_t i = (size_t)blockIdx.x * 256 + threadIdx.x;
    if (i >= (size_t)B_ * T_ * H_ / 8) return;
    const float4* p = (const float4*)xf + 2 * i;
    float4 a = p[0], b = p[1];
    Q o;
    o.h[0] = pkh2(a.x, a.y);
    o.h[1] = pkh2(a.z, a.w);
    o.h[2] = pkh2(b.x, b.y);
    o.h[3] = pkh2(b.z, b.w);
    ((uint4*)xh)[i] = o.u;
}

// ============================================================================
// FAST PATH: precompute input projections iproj[bt][3][64] f32.
// Same fdot2 accumulation order as the original in-loop version. v2: raw-f32
// register pipeline — issue row r+1's 16 float4 loads while computing row r
// (v1 serialized load-latency + compute per row -> ~210 us). 8 rows/group,
// 8192 blocks.
// ============================================================================
__global__ __launch_bounds__(256, 1)
void iproj_kernel(const float* __restrict__ xf, const __half* __restrict__ wit,
                  const float* __restrict__ b_ir, const float* __restrict__ b_iz,
                  const float* __restrict__ b_in, float* __restrict__ iproj) {
    const int lane = threadIdx.x & 63;
    const int grp  = threadIdx.x >> 6;   // 0..3
    Q wr[8], wz[8], wn[8];
    const uint4* wp = (const uint4*)wit + lane;
#pragma unroll
    for (int q = 0; q < 8; q++) {
        wr[q].u = wp[q * 64];
        wz[q].u = wp[512 + q * 64];
        wn[q].u = wp[1024 + q * 64];
    }
    const float bir = b_ir[lane], biz = b_iz[lane], bin = b_in[lane];
    const int bt_base = blockIdx.x * 32 + grp * 8;

    float4 raw[16];
    {
        const float4* xp = (const float4*)(xf + (size_t)bt_base * H_);
#pragma unroll
        for (int j = 0; j < 16; j++) raw[j] = xp[j];
    }
#pragma unroll
    for (int r = 0; r < 8; r++) {
        const int bt = bt_base + r;
        // convert current raw row to packed f16 (same pkh2 order as before)
        Q xq[8];
#pragma unroll
        for (int q = 0; q < 8; q++) {
            float4 a = raw[2 * q], b4 = raw[2 * q + 1];
            xq[q].h[0] = pkh2(a.x, a.y);
            xq[q].h[1] = pkh2(a.z, a.w);
            xq[q].h[2] = pkh2(b4.x, b4.y);
            xq[q].h[3] = pkh2(b4.z, b4.w);
        }
        // issue next row's loads (overlap with compute below)
        if (r < 7) {
            const float4* xp = (const float4*)(xf + (size_t)(bt + 1) * H_);
#pragma unroll
            for (int j = 0; j < 16; j++) raw[j] = xp[j];
        }
        float sir = bir, siz = biz, sin_ = bin;
#pragma unroll
        for (int q = 0; q < 8; q++)
#pragma unroll
            for (int p = 0; p < 4; p++) {
                sir  = fdot2f(wr[q].h[p], xq[q].h[p], sir);
                siz  = fdot2f(wz[q].h[p], xq[q].h[p], siz);
                sin_ = fdot2f(wn[q].h[p], xq[q].h[p], sin_);
            }
        float* op = iproj + (size_t)bt * 192;
        op[lane] = sir; op[64 + lane] = siz; op[128 + lane] = sin_;
    }
}

// ============================================================================
// FAST PATH sequential kernel gru_seq11: TWO independent chains per wave,
// ping-ponged gate-by-gate. The in-order wave fills chain0's DS/exp stalls
// with chain1's matvec (seq10's 1563 cyc/step had ~1000 cyc of bubbles and
// 1 wave/SIMD = nothing to fill them). No loop-carried W registers at all
// (seq7/seq9's RA failure mode): gate chunks are issued rolling (<=3 of 6
// live) and die within the step. iproj/ctx/mask prefetched 2 steps deep.
// 256 blocks x 64 threads (1 wave = 2 chains), 96 KB W image per block.
// ============================================================================
#define MVG(DST, W, HQ)                                                         \
    { float a4[4] = {0,0,0,0};                                                  \
      _Pragma("unroll") for (int q = 0; q < 8; q++)                             \
        _Pragma("unroll") for (int p = 0; p < 4; p++)                           \
          a4[q >> 1] = fdot2f(W[q].h[p], HQ[q].h[p], a4[q >> 1]);               \
      DST = (a4[0] + a4[1]) + (a4[2] + a4[3]); }

#define BSEL(K, A0, A1, A2, A3) (((K) == 0) ? (A0) : ((K) == 1) ? (A1) : ((K) == 2) ? (A2) : (A3))

#define STEP2(TT, BUF)                                                          \
{                                                                               \
    const int tt  = (TT);                                                       \
    const int tn2 = (tt + 2 < T_) ? tt + 2 : T_ - 1;                            \
    const uint4* w0 = sw + kc0 * 1536 + lane;                                   \
    const uint4* w1 = sw + kc1 * 1536 + lane;                                   \
    /* [A] issue r-gate LDS reads for both chains */                            \
    Q R0[8], R1[8];                                                             \
    _Pragma("unroll") for (int q = 0; q < 8; q++) R0[q].u = w0[q * 64];         \
    _Pragma("unroll") for (int q = 0; q < 8; q++) R1[q].u = w1[q * 64];         \
    /* [B] fill (independent of R0/R1): t+2 prefetch + bias selects */          \
    const int k2_0 = __builtin_amdgcn_readfirstlane(ctx[bt00 + tn2]);           \
    const int k2_1 = __builtin_amdgcn_readfirstlane(ctx[bt01 + tn2]);           \
    const unsigned char m2_0 = maskb[(size_t)(bt00 + tn2) << mshift];           \
    const unsigned char m2_1 = maskb[(size_t)(bt01 + tn2) << mshift];           \
    const float* ip2_0 = iproj + (size_t)(bt00 + tn2) * 192;                    \
    const float* ip2_1 = iproj + (size_t)(bt01 + tn2) * 192;                    \
    const float pr2_0 = ip2_0[lane], pz2_0 = ip2_0[64 + lane], pn2_0 = ip2_0[128 + lane]; \
    const float pr2_1 = ip2_1[lane], pz2_1 = ip2_1[64 + lane], pn2_1 = ip2_1[128 + lane]; \
    const float bhr0 = BSEL(kc0, bR0, bR1, bR2, bR3);                           \
    const float bhz0 = BSEL(kc0, bZ0, bZ1, bZ2, bZ3);                           \
    const float bhn0 = BSEL(kc0, bN0, bN1, bN2, bN3);                           \
    const float bhr1 = BSEL(kc1, bR0, bR1, bR2, bR3);                           \
    const float bhz1 = BSEL(kc1, bZ0, bZ1, bZ2, bZ3);                           \
    const float bhn1 = BSEL(kc1, bN0, bN1, bN2, bN3);                           \
    /* [C] ping-pong matvec: rolling gate-chunk issue, <=3 chunks live */       \
    float shr0, shr1, shz0, shz1, shn0, shn1;                                   \
    MVG(shr0, R0, hq0)                                                          \
    Q Z0[8];                                                                    \
    _Pragma("unroll") for (int q = 0; q < 8; q++) Z0[q].u = w0[512 + q * 64];   \
    MVG(shr1, R1, hq1)                                                          \
    Q Z1[8];                                                                    \
    _Pragma("unroll") for (int q = 0; q < 8; q++) Z1[q].u = w1[512 + q * 64];   \
    MVG(shz0, Z0, hq0)                                                          \
    Q N0[8];                                                                    \
    _Pragma("unroll") for (int q = 0; q < 8; q++) N0[q].u = w0[1024 + q * 64];  \
    MVG(shz1, Z1, hq1)                                                          \
    Q N1[8];                                                                    \
    _Pragma("unroll") for (int q = 0; q < 8; q++) N1[q].u = w1[1024 + q * 64];  \
    MVG(shn0, N0, hq0)                                                          \
    MVG(shn1, N1, hq1)                                                          \
    /* [D] epilogues (identical math/order to verified kernels) */              \
    const float arv0 = prc0 + shr0 + bhr0;                                      \
    const float azv0 = pzc0 + shz0 + bhz0;                                      \
    const float rr0  = 1.0f / (1.0f + __expf(-arv0));                           \
    const float zz0  = 1.0f / (1.0f + __expf(-azv0));                           \
    const float aa0  = pnc0 + rr0 * (shn0 + bhn0);                              \
    const float nn20 = 2.0f / (1.0f + __expf(-2.0f * aa0)) - 1.0f;              \
    float hnew0 = nn20 + zz0 * (hreg0 - nn20);                                  \
    hnew0 = (mc0 > 0.5f) ? hnew0 : hreg0;                                       \
    hreg0 = hnew0;                                                              \
    const float arv1 = prc1 + shr1 + bhr1;                                      \
    const float azv1 = pzc1 + shz1 + bhz1;                                      \
    const float rr1  = 1.0f / (1.0f + __expf(-arv1));                           \
    const float zz1  = 1.0f / (1.0f + __expf(-azv1));                           \
    const float aa1  = pnc1 + rr1 * (shn1 + bhn1);                              \
    const float nn21 = 2.0f / (1.0f + __expf(-2.0f * aa1)) - 1.0f;              \
    float hnew1 = nn21 + zz1 * (hreg1 - nn21);                                  \
    hnew1 = (mc1 > 0.5f) ? hnew1 : hreg1;                                       \
    hreg1 = hnew1;                                                              \
    const __half h16_0 = __float2half(hnew0);                                   \
    const __half h16_1 = __float2half(hnew1);                                   \
    /* [E] history stores + shared broadcast round trip */                      \
    hh0[(size_t)tt * H_ + lane] = h16_0;                                        \
    hh1[(size_t)tt * H_ + lane] = h16_1;                                        \
    hsc[((BUF) << 6) + lane] = h16_0;                                           \
    hsc[128 + ((BUF) << 6) + lane] = h16_1;                                     \
    __builtin_amdgcn_wave_barrier();                                            \
    { const uint4* hp0 = (const uint4*)(hsc + ((BUF) << 6));                    \
      const uint4* hp1 = (const uint4*)(hsc + 128 + ((BUF) << 6));              \
      _Pragma("unroll") for (int q = 0; q < 8; q++) {                           \
          hq0[q].u = hp0[q];                                                    \
          hq1[q].u = hp1[q];                                                    \
      } }                                                                       \
    __builtin_amdgcn_wave_barrier();                                            \
    /* [F] rotate 2-deep prefetch state */                                      \
    kc0 = kn0; kn0 = k2_0; kc1 = kn1; kn1 = k2_1;                               \
    mc0 = mn0; mn0 = m2_0 ? 1.0f : 0.0f;                                       \
    mc1 = mn1; mn1 = m2_1 ? 1.0f : 0.0f;                                       \
    prc0 = prn0; pzc0 = pzn0; pnc0 = pnn0;                                      \
    prn0 = pr2_0; pzn0 = pz2_0; pnn0 = pn2_0;                                   \
    prc1 = prn1; pzc1 = pzn1; pnc1 = pnn1;                                      \
    prn1 = pr2_1; pzn1 = pz2_1; pnn1 = pn2_1;                                   \
}

__global__ __launch_bounds__(64, 1)
void gru_seq11(const float* __restrict__ iproj, const int* __restrict__ ctx,
               const unsigned char* __restrict__ maskb, const int* __restrict__ flagp,
               const __half* __restrict__ wht,
               const float* __restrict__ b_hr, const float* __restrict__ b_hz,
               const float* __restrict__ b_hn, __half* __restrict__ hh) {
    extern __shared__ __align__(16) char smem[];
    uint4* sw = (uint4*)smem;            // Wh image (6144 u4)
    const int lane = threadIdx.x;        // 0..63, single wave

    // stage Wh into LDS once (unroll 8 to keep loads in flight)
    {
        const uint4* g = (const uint4*)wht;
#pragma unroll 8
        for (int i = lane; i < STAGE11_U4; i += 64) sw[i] = g[i];
    }
    __syncthreads();

    const int flag   = *flagp;
    const int mshift = flag ? 0 : 2;
    const int bt00   = (blockIdx.x * 2) * T_;
    const int bt01   = bt00 + T_;
    __half* hh0 = hh + (size_t)bt00 * H_;
    __half* hh1 = hh + (size_t)bt01 * H_;
    __half* hsc = (__half*)(smem + LDS11_HSC_OFF);   // [chain:2][buf:2][64]

    // expert biases -> registers (12 VGPRs)
    const float bR0 = b_hr[lane],       bR1 = b_hr[64 + lane];
    const float bR2 = b_hr[128 + lane], bR3 = b_hr[192 + lane];
    const float bZ0 = b_hz[lane],       bZ1 = b_hz[64 + lane];
    const float bZ2 = b_hz[128 + lane], bZ3 = b_hz[192 + lane];
    const float bN0 = b_hn[lane],       bN1 = b_hn[64 + lane];
    const float bN2 = b_hn[128 + lane], bN3 = b_hn[192 + lane];

    float hreg0 = 0.0f, hreg1 = 0.0f;
    Q hq0[8], hq1[8];
#pragma unroll
    for (int q = 0; q < 8; q++) {
        hq0[q].u = make_uint4(0u, 0u, 0u, 0u);
        hq1[q].u = make_uint4(0u, 0u, 0u, 0u);
    }

    // 2-deep scalar/iproj prefetch pipeline, both chains
    int kc0 = __builtin_amdgcn_readfirstlane(ctx[bt00]);
    int kn0 = __builtin_amdgcn_readfirstlane(ctx[bt00 + 1]);
    int kc1 = __builtin_amdgcn_readfirstlane(ctx[bt01]);
    int kn1 = __builtin_amdgcn_readfirstlane(ctx[bt01 + 1]);
    float mc0 = maskb[(size_t)bt00 << mshift] ? 1.0f : 0.0f;
    float mn0 = maskb[(size_t)(bt00 + 1) << mshift] ? 1.0f : 0.0f;
    float mc1 = maskb[(size_t)bt01 << mshift] ? 1.0f : 0.0f;
    float mn1 = maskb[(size_t)(bt01 + 1) << mshift] ? 1.0f : 0.0f;
    const float* ip;
    ip = iproj + (size_t)bt00 * 192;
    float prc0 = ip[lane], pzc0 = ip[64 + lane], pnc0 = ip[128 + lane];
    ip = iproj + (size_t)(bt00 + 1) * 192;
    float prn0 = ip[lane], pzn0 = ip[64 + lane], pnn0 = ip[128 + lane];
    ip = iproj + (size_t)bt01 * 192;
    float prc1 = ip[lane], pzc1 = ip[64 + lane], pnc1 = ip[128 + lane];
    ip = iproj + (size_t)(bt01 + 1) * 192;
    float prn1 = ip[lane], pzn1 = ip[64 + lane], pnn1 = ip[128 + lane];

#pragma unroll 1
    for (int t = 0; t < T_; t += 2) {
        STEP2(t,     0)
        STEP2(t + 1, 1)
    }
}

// logits from stored f16 h history: out[bt][o] = sum_h hh[bt][h]*Wo_w[o][h] + Wo_b[o]
__global__ __launch_bounds__(256, 1)
void logits_kernel(const __half* __restrict__ hh, const float* __restrict__ Wo_w,
                   const float* __restrict__ Wo_b, float* __restrict__ out) {
    const int bt = blockIdx.x * 256 + threadIdx.x;
    const uint4* hp = (const uint4*)(hh + (size_t)bt * H_);
    const float wob0 = Wo_b[0], wob1 = Wo_b[1];
    float l0 = 0.0f, l1 = 0.0f;
#pragma unroll
    for (int q = 0; q < 8; q++) {
        Q h8; h8.u = hp[q];
#pragma unroll
        for (int p = 0; p < 4; p++) {
            const int j = q * 8 + p * 2;
            const float v0 = (float)h8.h[p][0];
            const float v1 = (float)h8.h[p][1];
            l0 = fmaf(v0, Wo_w[j], l0);
            l0 = fmaf(v1, Wo_w[j + 1], l0);
            l1 = fmaf(v0, Wo_w[64 + j], l1);
            l1 = fmaf(v1, Wo_w[64 + j + 1], l1);
        }
    }
    *(float2*)(out + (size_t)bt * 2) = make_float2(l0 + wob0, l1 + wob1);
}

// ============================================================================
// FALLBACK PATH (ws too small for iproj): verified gru_seq6, unchanged.
// ============================================================================
#define STEP(TT, WCUR, WNXT, BUF)                                              \
{                                                                              \
    const int tt = (TT);                                                       \
    const int tn = (tt + 1 < T_) ? tt + 1 : T_ - 1;                            \
    Q xq[8];                                                                   \
    { const uint4* xp = (const uint4*)(xh16 + (size_t)(bt0 + tt) * H_);        \
      _Pragma("unroll") for (int q = 0; q < 8; q++) xq[q].u = xp[q]; }         \
    float ar4[4] = {0,0,0,0}, az4[4] = {0,0,0,0}, an4[4] = {0,0,0,0};          \
    _Pragma("unroll") for (int q = 0; q < 8; q++) {                            \
        _Pragma("unroll") for (int p = 0; p < 4; p++) {                        \
            ar4[q >> 1] = fdot2f(WCUR[q].h[p],      hq[q].h[p], ar4[q >> 1]);  \
            az4[q >> 1] = fdot2f(WCUR[8 + q].h[p],  hq[q].h[p], az4[q >> 1]);  \
            an4[q >> 1] = fdot2f(WCUR[16 + q].h[p], hq[q].h[p], an4[q >> 1]);  \
        }                                                                      \
    }                                                                          \
    const float shr = (ar4[0] + ar4[1]) + (ar4[2] + ar4[3]);                   \
    const float shz = (az4[0] + az4[1]) + (az4[2] + az4[3]);                   \
    const float shn = (an4[0] + an4[1]) + (an4[2] + an4[3]);                   \
    float sir = bir, siz = biz, sin_ = bin;                                    \
    _Pragma("unroll") for (int q = 0; q < 8; q++) {                            \
        Q wr, wz, wn;                                                          \
        wr.u = swi[q * 64 + lane];                                             \
        wz.u = swi[512 + q * 64 + lane];                                       \
        wn.u = swi[1024 + q * 64 + lane];                                      \
        _Pragma("unroll") for (int p = 0; p < 4; p++) {                        \
            sir  = fdot2f(wr.h[p], xq[q].h[p], sir);                           \
            siz  = fdot2f(wz.h[p], xq[q].h[p], siz);                           \
            sin_ = fdot2f(wn.h[p], xq[q].h[p], sin_);                          \
        }                                                                      \
    }                                                                          \
    const int kn = __builtin_amdgcn_readfirstlane(ctx[bt0 + tn]);              \
    const unsigned char mn = maskb[(size_t)(bt0 + tn) << mshift];              \
    const float bhr_n = b_hr[kn * H_ + lane];                                  \
    const float bhz_n = b_hz[kn * H_ + lane];                                  \
    const float bhn_n = b_hn[kn * H_ + lane];                                  \
    { const uint4* wp = sw + kn * 1536 + lane;                                 \
      _Pragma("unroll") for (int q = 0; q < 8; q++) {                          \
        WNXT[q].u      = wp[q * 64];                                           \
        WNXT[8 + q].u  = wp[512 + q * 64];                                     \
        WNXT[16 + q].u = wp[1024 + q * 64];                                    \
      } }                                                                      \
    const float arv = sir + shr + bhr_c;                                       \
    const float azv = siz + shz + bhz_c;                                       \
    const float rr  = 1.0f / (1.0f + __expf(-arv));                            \
    const float zz  = 1.0f / (1.0f + __expf(-azv));                            \
    const float aa  = sin_ + rr * (shn + bhn_c);                               \
    const float nn2 = 2.0f / (1.0f + __expf(-2.0f * aa)) - 1.0f;               \
    float hnew = nn2 + zz * (hreg - nn2);                                      \
    hnew = (mc > 0.5f) ? hnew : hreg;                                          \
    hreg = hnew;                                                               \
    { __half* hb = hsc + ((BUF) << 6);                                         \
      hb[lane] = __float2half(hnew);                                           \
      __builtin_amdgcn_wave_barrier();                                         \
      const uint4* hp = (const uint4*)hb;                                      \
      _Pragma("unroll") for (int q = 0; q < 8; q++) hq[q].u = hp[q];           \
      __builtin_amdgcn_wave_barrier(); }                                       \
    { float l0 = hnew * wo0, l1 = hnew * wo1;                                  \
      _Pragma("unroll") for (int m = 32; m >= 1; m >>= 1) {                    \
          l0 += __shfl_xor(l0, m, 64);                                         \
          l1 += __shfl_xor(l1, m, 64);                                         \
      }                                                                        \
      if (lane == 0) *(float2*)(outp + tt * 2) = make_float2(l0 + wob0, l1 + wob1); } \
    bhr_c = bhr_n; bhz_c = bhz_n; bhn_c = bhn_n;                               \
    mc = mn ? 1.0f : 0.0f;                                                     \
}

__global__ __launch_bounds__(128, 1)
void gru_seq6(const __half* __restrict__ xh16, const int* __restrict__ ctx,
              const unsigned char* __restrict__ maskb, const int* __restrict__ flagp,
              const __half* __restrict__ wht,
              const float* __restrict__ b_ir, const float* __restrict__ b_iz,
              const float* __restrict__ b_in, const float* __restrict__ b_hr,
              const float* __restrict__ b_hz, const float* __restrict__ b_hn,
              const float* __restrict__ Wo_w, const float* __restrict__ Wo_b,
              float* __restrict__ out) {
    extern __shared__ __align__(16) char smem[];
    uint4* sw  = (uint4*)smem;          // Wh image (6144 u4)
    uint4* swi = sw + 6144;             // Wi image (1536 u4)

    const int tid  = threadIdx.x;
    const int lane = tid & 63;
    const int wv   = tid >> 6;          // 0,1
    const int b    = blockIdx.x * 2 + wv;

    {
        const uint4* gsrc = (const uint4*)wht;
#pragma unroll 1
        for (int i = tid; i < STAGE_U4; i += 128) sw[i] = gsrc[i];
    }
    __syncthreads();

    const int flag   = *flagp;
    const int mshift = flag ? 0 : 2;
    const int bt0    = b * T_;

    const float bir = b_ir[lane], biz = b_iz[lane], bin = b_in[lane];
    const float wo0 = Wo_w[lane], wo1 = Wo_w[64 + lane];
    const float wob0 = Wo_b[0], wob1 = Wo_b[1];

    __half* hsc = (__half*)(smem + LDS_HSC_OFF + (wv << 8));
    float*  outp = out + (size_t)b * T_ * 2;

    float hreg = 0.0f;
    Q hq[8];
#pragma unroll
    for (int q = 0; q < 8; q++) hq[q].u = make_uint4(0u, 0u, 0u, 0u);

    Q wA[24], wB[24];
    const int k0 = __builtin_amdgcn_readfirstlane(ctx[bt0]);
    float mc = maskb[(size_t)bt0 << mshift] ? 1.0f : 0.0f;
    float bhr_c = b_hr[k0 * H_ + lane];
    float bhz_c = b_hz[k0 * H_ + lane];
    float bhn_c = b_hn[k0 * H_ + lane];
    {
        const uint4* wp = sw + k0 * 1536 + lane;
#pragma unroll
        for (int q = 0; q < 8; q++) {
            wA[q].u      = wp[q * 64];
            wA[8 + q].u  = wp[512 + q * 64];
            wA[16 + q].u = wp[1024 + q * 64];
        }
    }

#pragma unroll 1
    for (int t = 0; t < T_; t += 2) {
        STEP(t,     wA, wB, 0)
        STEP(t + 1, wB, wA, 1)
    }
}

extern "C" void kernel_launch(void* const* d_in, const int* in_sizes, int n_in,
                              void* d_out, int out_size, void* d_ws, size_t ws_size,
                              hipStream_t stream) {
    const float* x    = (const float*)d_in[0];
    const int*   ctx  = (const int*)d_in[1];
    const void*  mask = d_in[2];
    const float* W_ir = (const float*)d_in[3];
    const float* W_iz = (const float*)d_in[4];
    const float* W_in = (const float*)d_in[5];
    const float* bir  = (const float*)d_in[6];
    const float* biz  = (const float*)d_in[7];
    const float* bin  = (const float*)d_in[8];
    const float* W_hr = (const float*)d_in[9];
    const float* W_hz = (const float*)d_in[10];
    const float* W_hn = (const float*)d_in[11];
    const float* bhr  = (const float*)d_in[12];
    const float* bhz  = (const float*)d_in[13];
    const float* bhn  = (const float*)d_in[14];
    const float* Wo_w = (const float*)d_in[15];
    const float* Wo_b = (const float*)d_in[16];

    char* ws = (char*)d_ws;
    __half* wht  = (__half*)ws;
    __half* wit  = (__half*)(ws + WS_WIT_OFF);
    int*    flag = (int*)(ws + WS_FLAG_OFF);

    detect_mask_kernel<<<1, 256, 0, stream>>>((const unsigned char*)mask, flag);
    convert_weights_kernel<<<192, 256, 0, stream>>>(W_hr, W_hz, W_hn, W_ir, W_iz, W_in,
                                                    wht, wit);

    if (ws_size >= (size_t)WS_NEED_FAST) {
        // fast path: pipelined iproj + 2-chain-per-wave sequence + deferred logits
        float*  iproj = (float*)(ws + WS_IPJ_OFF);
        __half* hh    = (__half*)(ws + WS_HH_OFF);
        iproj_kernel<<<B_ * T_ / 32, 256, 0, stream>>>(x, wit, bir, biz, bin, iproj);
        (void)hipFuncSetAttribute((const void*)gru_seq11,
                                  hipFuncAttributeMaxDynamicSharedMemorySize, LDS11_TOTAL);
        gru_seq11<<<B_ / 2, 64, LDS11_TOTAL, stream>>>(
            iproj, ctx, (const unsigned char*)mask, flag, wht, bhr, bhz, bhn, hh);
        logits_kernel<<<B_ * T_ / 256, 256, 0, stream>>>(hh, Wo_w, Wo_b, (float*)d_out);
    } else {
        // fallback: previous verified pipeline
        __half* xh16 = (__half*)(ws + WS_XH_OFF);
        convert_x_kernel<<<8192, 256, 0, stream>>>(x, xh16);
        (void)hipFuncSetAttribute((const void*)gru_seq6,
                                  hipFuncAttributeMaxDynamicSharedMemorySize, LDS_TOTAL);
        gru_seq6<<<B_ / 2, 128, LDS_TOTAL, stream>>>(
            xh16, ctx, (const unsigned char*)mask, flag, wht,
            bir, biz, bin, bhr, bhz, bhn, Wo_w, Wo_b, (float*)d_out);
    }
}

// Round 7
// 588.236 us; speedup vs baseline: 1.8619x; 1.8619x over previous
//
#include <hip/hip_runtime.h>
#include <hip/hip_fp16.h>

#define B_ 512
#define T_ 512
#define H_ 64
#define K_ 4

// ---- workspace layout (shared prefix, both paths) ----
//   wht  f16 [K*3][8][64][8]  @ 0        (98304 B)  chunk-transposed W_h
//   wit  f16 [3][8][64][8]    @ 98304    (24576 B)  chunk-transposed W_i
//   flag int                  @ 123136
// fallback path:
//   xh16 f16 [B*T*H]          @ 131072   (33554432 B)
// fast path:
//   iproj f32 [B*T][3][64]    @ 131072   (201326592 B)
//   hh    f16 [B*T][64]       @ 201457664 (33554432 B)
#define WS_WIT_OFF   98304
#define WS_FLAG_OFF  123136
#define WS_XH_OFF    131072
#define WS_IPJ_OFF   131072
#define WS_HH_OFF    201457664ULL
#define WS_NEED_FAST 235012096ULL

// fallback LDS (gru_seq6): Wh [0,98304) ; Wi [98304,122880) ; h scratch @122880
#define LDS_HSC_OFF  122880
#define LDS_TOTAL    123392
#define STAGE_U4     7680

// fast-path LDS (gru_seq12): Wh [0,98304) ; h scratch @98304
//   h scratch: [wave:2][buf:2][64 halves] = 512 B
#define LDS12_HSC_OFF 98304
#define LDS12_TOTAL   98816
#define STAGE12_U4    6144

typedef _Float16 half2_t __attribute__((ext_vector_type(2)));

union Q { uint4 u; half2_t h[4]; };  // 16 B = 4 packed half2

__device__ __forceinline__ float fdot2f(half2_t a, half2_t b, float c) {
#if __has_builtin(__builtin_amdgcn_fdot2)
    return __builtin_amdgcn_fdot2(a, b, c, false);
#else
    return fmaf((float)a[0], (float)b[0], fmaf((float)a[1], (float)b[1], c));
#endif
}

__device__ __forceinline__ half2_t pkh2(float a, float b) {
    return __builtin_bit_cast(half2_t, __builtin_amdgcn_cvt_pkrtz(a, b));
}

// Detect whether mask buffer is 1-byte bools or int32 0/1 (little-endian).
__global__ void detect_mask_kernel(const unsigned char* __restrict__ mb, int* __restrict__ flag) {
    __shared__ int cnt;
    if (threadIdx.x == 0) cnt = 0;
    __syncthreads();
    int c = 0;
    for (int i = threadIdx.x; i < 4096; i += blockDim.x)
        if ((i & 3) != 0 && mb[i] != 0) c++;
    atomicAdd(&cnt, c);
    __syncthreads();
    if (threadIdx.x == 0) *flag = (cnt > 0) ? 1 : 0;  // 1 => uint8 bools, 0 => int32
}

// Weights -> f16 chunk-transposed: dst u4 index (mat*8 + j/8)*64 + i
__global__ void convert_weights_kernel(const float* __restrict__ Whr, const float* __restrict__ Whz,
                                       const float* __restrict__ Whn, const float* __restrict__ Wir,
                                       const float* __restrict__ Wiz, const float* __restrict__ Win,
                                       __half* __restrict__ wht, __half* __restrict__ wit) {
    int idx = blockIdx.x * 256 + threadIdx.x;
    if (idx < K_ * 3 * H_ * H_) {
        int mat = idx >> 12;            // k*3+g
        int i   = (idx >> 6) & 63;
        int j   = idx & 63;
        int k   = mat / 3, g = mat - 3 * k;
        const float* src = (g == 0) ? Whr : (g == 1) ? Whz : Whn;
        wht[((mat * 8 + (j >> 3)) * 64 + i) * 8 + (j & 7)] = __float2half(src[(k * H_ + i) * H_ + j]);
    }
    if (idx < 3 * H_ * H_) {
        int g = idx >> 12;
        int i = (idx >> 6) & 63;
        int j = idx & 63;
        const float* src = (g == 0) ? Wir : (g == 1) ? Wiz : Win;
        wit[((g * 8 + (j >> 3)) * 64 + i) * 8 + (j & 7)] = __float2half(src[i * H_ + j]);
    }
}

// x f32 -> packed f16 (fallback path only)
__global__ void convert_x_kernel(const float* __restrict__ xf, __half* __restrict__ xh) {
    size_t i = (size_t)blockIdx.x * 256 + threadIdx.x;
    if (i >= (size_t)B_ * T_ * H_ / 8) return;
    const float4* p = (const float4*)xf + 2 * i;
    float4 a = p[0], b = p[1];
    Q o;
    o.h[0] = pkh2(a.x, a.y);
    o.h[1] = pkh2(a.z, a.w);
    o.h[2] = pkh2(b.x, b.y);
    o.h[3] = pkh2(b.z, b.w);
    ((uint4*)xh)[i] = o.u;
}

// ============================================================================
// FAST PATH: precompute input projections iproj[bt][3][64] f32.
// Same fdot2 accumulation order as the original in-loop version. Pipelined:
// issue row r+1's 16 float4 loads while computing row r.
// ============================================================================
__global__ __launch_bounds__(256, 1)
void iproj_kernel(const float* __restrict__ xf, const __half* __restrict__ wit,
                  const float* __restrict__ b_ir, const float* __restrict__ b_iz,
                  const float* __restrict__ b_in, float* __restrict__ iproj) {
    const int lane = threadIdx.x & 63;
    const int grp  = threadIdx.x >> 6;   // 0..3
    Q wr[8], wz[8], wn[8];
    const uint4* wp = (const uint4*)wit + lane;
#pragma unroll
    for (int q = 0; q < 8; q++) {
        wr[q].u = wp[q * 64];
        wz[q].u = wp[512 + q * 64];
        wn[q].u = wp[1024 + q * 64];
    }
    const float bir = b_ir[lane], biz = b_iz[lane], bin = b_in[lane];
    const int bt_base = blockIdx.x * 32 + grp * 8;

    float4 raw[16];
    {
        const float4* xp = (const float4*)(xf + (size_t)bt_base * H_);
#pragma unroll
        for (int j = 0; j < 16; j++) raw[j] = xp[j];
    }
#pragma unroll
    for (int r = 0; r < 8; r++) {
        const int bt = bt_base + r;
        Q xq[8];
#pragma unroll
        for (int q = 0; q < 8; q++) {
            float4 a = raw[2 * q], b4 = raw[2 * q + 1];
            xq[q].h[0] = pkh2(a.x, a.y);
            xq[q].h[1] = pkh2(a.z, a.w);
            xq[q].h[2] = pkh2(b4.x, b4.y);
            xq[q].h[3] = pkh2(b4.z, b4.w);
        }
        if (r < 7) {
            const float4* xp = (const float4*)(xf + (size_t)(bt + 1) * H_);
#pragma unroll
            for (int j = 0; j < 16; j++) raw[j] = xp[j];
        }
        float sir = bir, siz = biz, sin_ = bin;
#pragma unroll
        for (int q = 0; q < 8; q++)
#pragma unroll
            for (int p = 0; p < 4; p++) {
                sir  = fdot2f(wr[q].h[p], xq[q].h[p], sir);
                siz  = fdot2f(wz[q].h[p], xq[q].h[p], siz);
                sin_ = fdot2f(wn[q].h[p], xq[q].h[p], sin_);
            }
        float* op = iproj + (size_t)bt * 192;
        op[lane] = sir; op[64 + lane] = siz; op[128 + lane] = sin_;
    }
}

// ============================================================================
// FAST PATH sequential kernel gru_seq12 = seq10's chassis (333 us, VGPR 80)
// + INLINE-ASM-PINNED full next-step weight prefetch. hipcc sinks any
// compiler-visible >=96-VGPR weight buffer to its uses (seq6/7/9/11: VGPR
// 88-140, LDS latency serialized). An asm volatile ds_read_b128 with "=v"
// output is a hard SSA def the RA MUST keep in arch VGPRs — it cannot sink
// or rematerialize it. Per step: 24 asm reads at step top fetch ALL gates of
// the NEXT step's expert (k from the chunked ctx pipeline) into wNext[24]
// (96 VGPR); the current matvec runs entirely on registers. Per guide rule
// #18, s_waitcnt lgkmcnt(0) + sched_barrier(0) at step end (LDS completes
// in-order, so this is nearly free after the h round-trip) fences the asm
// results before their next-step use. Steady-state loop: zero global loads,
// zero compiler LDS weight reads. 256 blocks x 128 thr, 96 KB W image.
// ============================================================================
#define DSR(DST, ADDR, OFF) \
    asm volatile("ds_read_b128 %0, %1 offset:" #OFF : "=v"(DST) : "v"(ADDR));

#define PREF24(WN, VB)                                                          \
    DSR(WN[0].u,  VB, 0)     DSR(WN[1].u,  VB, 1024)                            \
    DSR(WN[2].u,  VB, 2048)  DSR(WN[3].u,  VB, 3072)                            \
    DSR(WN[4].u,  VB, 4096)  DSR(WN[5].u,  VB, 5120)                            \
    DSR(WN[6].u,  VB, 6144)  DSR(WN[7].u,  VB, 7168)                            \
    DSR(WN[8].u,  VB, 8192)  DSR(WN[9].u,  VB, 9216)                            \
    DSR(WN[10].u, VB, 10240) DSR(WN[11].u, VB, 11264)                           \
    DSR(WN[12].u, VB, 12288) DSR(WN[13].u, VB, 13312)                           \
    DSR(WN[14].u, VB, 14336) DSR(WN[15].u, VB, 15360)                           \
    DSR(WN[16].u, VB, 16384) DSR(WN[17].u, VB, 17408)                           \
    DSR(WN[18].u, VB, 18432) DSR(WN[19].u, VB, 19456)                           \
    DSR(WN[20].u, VB, 20480) DSR(WN[21].u, VB, 21504)                           \
    DSR(WN[22].u, VB, 22528) DSR(WN[23].u, VB, 23552)

#define BSEL(K, A0, A1, A2, A3) (((K) == 0) ? (A0) : ((K) == 1) ? (A1) : ((K) == 2) ? (A2) : (A3))

#define LOADCHUNK(IPR, IPZ, IPN, CTXV, MSKV, T0)                                \
{                                                                               \
    const int t0c = (T0);                                                       \
    _Pragma("unroll") for (int s = 0; s < 8; s++) {                             \
        int tcl = t0c + s; tcl = (tcl < T_) ? tcl : (T_ - 1);                   \
        const float* ipp = iproj + (size_t)(bt0 + tcl) * 192;                   \
        IPR[s] = ipp[lane]; IPZ[s] = ipp[64 + lane]; IPN[s] = ipp[128 + lane];  \
    }                                                                           \
    int tcc = t0c + (lane & 7); tcc = (tcc < T_) ? tcc : (T_ - 1);              \
    CTXV = ctx[bt0 + tcc];                                                      \
    MSKV = (int)maskb[(size_t)(bt0 + tcc) << mshift];                           \
}

#define STEP12(TT, SS, WCUR, WNXT, KNU_EXPR, IPR, IPZ, IPN, CTXC, MSKC)         \
{                                                                               \
    const int tt  = (TT);                                                       \
    const int kcu = __builtin_amdgcn_readlane(CTXC, SS);                        \
    const int knu = (KNU_EXPR);                                                 \
    /* asm-pinned prefetch: all 3 gates of next step's expert -> WNXT */        \
    const unsigned int vb = lds0 + (unsigned int)(knu * 24576) + ((unsigned int)lane << 4); \
    PREF24(WNXT, vb)                                                            \
    /* matvec on register-resident WCUR (verified accumulation order) */        \
    float ar4[4] = {0,0,0,0}, az4[4] = {0,0,0,0}, an4[4] = {0,0,0,0};           \
    _Pragma("unroll") for (int q = 0; q < 8; q++) {                             \
        _Pragma("unroll") for (int p = 0; p < 4; p++) {                         \
            ar4[q >> 1] = fdot2f(WCUR[q].h[p],      hq[q].h[p], ar4[q >> 1]);   \
            az4[q >> 1] = fdot2f(WCUR[8 + q].h[p],  hq[q].h[p], az4[q >> 1]);   \
            an4[q >> 1] = fdot2f(WCUR[16 + q].h[p], hq[q].h[p], an4[q >> 1]);   \
        }                                                                       \
    }                                                                           \
    const float shr = (ar4[0] + ar4[1]) + (ar4[2] + ar4[3]);                    \
    const float shz = (az4[0] + az4[1]) + (az4[2] + az4[3]);                    \
    const float shn = (an4[0] + an4[1]) + (an4[2] + an4[3]);                    \
    /* expert bias select (register-resident, uniform k) + mask */              \
    const float bhr = BSEL(kcu, bR0, bR1, bR2, bR3);                            \
    const float bhz = BSEL(kcu, bZ0, bZ1, bZ2, bZ3);                            \
    const float bhn = BSEL(kcu, bN0, bN1, bN2, bN3);                            \
    const float mcv = (__builtin_amdgcn_readlane(MSKC, SS) != 0) ? 1.0f : 0.0f; \
    /* epilogue (identical math/order to verified kernels) */                   \
    const float arv = IPR[SS] + shr + bhr;                                      \
    const float azv = IPZ[SS] + shz + bhz;                                      \
    const float rr  = 1.0f / (1.0f + __expf(-arv));                             \
    const float zz  = 1.0f / (1.0f + __expf(-azv));                             \
    const float aa  = IPN[SS] + rr * (shn + bhn);                               \
    const float nn2 = 2.0f / (1.0f + __expf(-2.0f * aa)) - 1.0f;                \
    float hnew = nn2 + zz * (hreg - nn2);                                       \
    hnew = (mcv > 0.5f) ? hnew : hreg;                                          \
    hreg = hnew;                                                                \
    const __half h16 = __float2half(hnew);                                      \
    hsc[((SS & 1) << 6) + lane] = h16;                                          \
    hh0[(size_t)tt * H_ + lane] = h16;        /* fire-and-forget history */     \
    __builtin_amdgcn_wave_barrier();                                            \
    { const uint4* hp = (const uint4*)(hsc + ((SS & 1) << 6));                  \
      _Pragma("unroll") for (int q = 0; q < 8; q++) hq[q].u = hp[q]; }          \
    __builtin_amdgcn_wave_barrier();                                            \
    /* fence: asm reads done before next step's matvec (rule #18) */            \
    asm volatile("s_waitcnt lgkmcnt(0)" ::: "memory");                          \
    __builtin_amdgcn_sched_barrier(0);                                          \
}

#define RUNCHUNK12(T0, IPR, IPZ, IPN, CTXC, MSKC, CTXN)                         \
    STEP12(T0 + 0, 0, wA, wB, __builtin_amdgcn_readlane(CTXC, 1), IPR, IPZ, IPN, CTXC, MSKC) \
    STEP12(T0 + 1, 1, wB, wA, __builtin_amdgcn_readlane(CTXC, 2), IPR, IPZ, IPN, CTXC, MSKC) \
    STEP12(T0 + 2, 2, wA, wB, __builtin_amdgcn_readlane(CTXC, 3), IPR, IPZ, IPN, CTXC, MSKC) \
    STEP12(T0 + 3, 3, wB, wA, __builtin_amdgcn_readlane(CTXC, 4), IPR, IPZ, IPN, CTXC, MSKC) \
    STEP12(T0 + 4, 4, wA, wB, __builtin_amdgcn_readlane(CTXC, 5), IPR, IPZ, IPN, CTXC, MSKC) \
    STEP12(T0 + 5, 5, wB, wA, __builtin_amdgcn_readlane(CTXC, 6), IPR, IPZ, IPN, CTXC, MSKC) \
    STEP12(T0 + 6, 6, wA, wB, __builtin_amdgcn_readlane(CTXC, 7), IPR, IPZ, IPN, CTXC, MSKC) \
    STEP12(T0 + 7, 7, wB, wA, __builtin_amdgcn_readlane(CTXN, 0), IPR, IPZ, IPN, CTXC, MSKC)

__global__ __launch_bounds__(128, 1)
void gru_seq12(const float* __restrict__ iproj, const int* __restrict__ ctx,
               const unsigned char* __restrict__ maskb, const int* __restrict__ flagp,
               const __half* __restrict__ wht,
               const float* __restrict__ b_hr, const float* __restrict__ b_hz,
               const float* __restrict__ b_hn, __half* __restrict__ hh) {
    extern __shared__ __align__(16) char smem[];
    uint4* sw = (uint4*)smem;            // Wh image (6144 u4)

    const int tid  = threadIdx.x;
    const int lane = tid & 63;
    const int wv   = tid >> 6;           // 0,1
    const int b    = blockIdx.x * 2 + wv;
    const int bt0  = b * T_;

    // stage Wh into LDS once (both waves cooperate)
    {
        const uint4* g = (const uint4*)wht;
#pragma unroll 1
        for (int i = tid; i < STAGE12_U4; i += 128) sw[i] = g[i];
    }
    __syncthreads();

    // LDS byte base (gfx9+ apertures are 4 GB aligned: low 32 bits of the
    // generic address of dynamic LDS = LDS byte offset)
    const unsigned int lds0 = (unsigned int)(uintptr_t)smem;

    const int flag   = *flagp;
    const int mshift = flag ? 0 : 2;
    __half* hh0 = hh + (size_t)bt0 * H_;
    __half* hsc = (__half*)(smem + LDS12_HSC_OFF + (wv << 8));

    // expert biases -> registers (12 VGPRs)
    const float bR0 = b_hr[lane],       bR1 = b_hr[64 + lane];
    const float bR2 = b_hr[128 + lane], bR3 = b_hr[192 + lane];
    const float bZ0 = b_hz[lane],       bZ1 = b_hz[64 + lane];
    const float bZ2 = b_hz[128 + lane], bZ3 = b_hz[192 + lane];
    const float bN0 = b_hn[lane],       bN1 = b_hn[64 + lane];
    const float bN2 = b_hn[128 + lane], bN3 = b_hn[192 + lane];

    float hreg = 0.0f;
    Q hq[8];
#pragma unroll
    for (int q = 0; q < 8; q++) hq[q].u = make_uint4(0u, 0u, 0u, 0u);

    // double-buffered 8-step chunks of iproj/ctx/mask
    float ipAr[8], ipAz[8], ipAn[8];
    float ipBr[8], ipBz[8], ipBn[8];
    int ctxA, mskA, ctxB, mskB;
    LOADCHUNK(ipAr, ipAz, ipAn, ctxA, mskA, 0)

    // prologue: W_h[k(0)] -> wA (compiler reads; auto-waited)
    Q wA[24], wB[24];
    {
        const int k0u = __builtin_amdgcn_readlane(ctxA, 0);
        const uint4* wp0 = sw + k0u * 1536 + lane;
#pragma unroll
        for (int q = 0; q < 8; q++) {
            wA[q].u      = wp0[q * 64];
            wA[8 + q].u  = wp0[512 + q * 64];
            wA[16 + q].u = wp0[1024 + q * 64];
        }
    }

#pragma unroll 1
    for (int c = 0; c < 64; c += 2) {
        const int t0a = c << 3, t0b = t0a + 8;
        LOADCHUNK(ipBr, ipBz, ipBn, ctxB, mskB, t0b)
        RUNCHUNK12(t0a, ipAr, ipAz, ipAn, ctxA, mskA, ctxB)
        LOADCHUNK(ipAr, ipAz, ipAn, ctxA, mskA, t0b + 8)
        RUNCHUNK12(t0b, ipBr, ipBz, ipBn, ctxB, mskB, ctxA)
    }
}

// logits from stored f16 h history: out[bt][o] = sum_h hh[bt][h]*Wo_w[o][h] + Wo_b[o]
__global__ __launch_bounds__(256, 1)
void logits_kernel(const __half* __restrict__ hh, const float* __restrict__ Wo_w,
                   const float* __restrict__ Wo_b, float* __restrict__ out) {
    const int bt = blockIdx.x * 256 + threadIdx.x;
    const uint4* hp = (const uint4*)(hh + (size_t)bt * H_);
    const float wob0 = Wo_b[0], wob1 = Wo_b[1];
    float l0 = 0.0f, l1 = 0.0f;
#pragma unroll
    for (int q = 0; q < 8; q++) {
        Q h8; h8.u = hp[q];
#pragma unroll
        for (int p = 0; p < 4; p++) {
            const int j = q * 8 + p * 2;
            const float v0 = (float)h8.h[p][0];
            const float v1 = (float)h8.h[p][1];
            l0 = fmaf(v0, Wo_w[j], l0);
            l0 = fmaf(v1, Wo_w[j + 1], l0);
            l1 = fmaf(v0, Wo_w[64 + j], l1);
            l1 = fmaf(v1, Wo_w[64 + j + 1], l1);
        }
    }
    *(float2*)(out + (size_t)bt * 2) = make_float2(l0 + wob0, l1 + wob1);
}

// ============================================================================
// FALLBACK PATH (ws too small for iproj): verified gru_seq6, unchanged.
// ============================================================================
#define STEP(TT, WCUR, WNXT, BUF)                                              \
{                                                                              \
    const int tt = (TT);                                                       \
    const int tn = (tt + 1 < T_) ? tt + 1 : T_ - 1;                            \
    Q xq[8];                                                                   \
    { const uint4* xp = (const uint4*)(xh16 + (size_t)(bt0 + tt) * H_);        \
      _Pragma("unroll") for (int q = 0; q < 8; q++) xq[q].u = xp[q]; }         \
    float ar4[4] = {0,0,0,0}, az4[4] = {0,0,0,0}, an4[4] = {0,0,0,0};          \
    _Pragma("unroll") for (int q = 0; q < 8; q++) {                            \
        _Pragma("unroll") for (int p = 0; p < 4; p++) {                        \
            ar4[q >> 1] = fdot2f(WCUR[q].h[p],      hq[q].h[p], ar4[q >> 1]);  \
            az4[q >> 1] = fdot2f(WCUR[8 + q].h[p],  hq[q].h[p], az4[q >> 1]);  \
            an4[q >> 1] = fdot2f(WCUR[16 + q].h[p], hq[q].h[p], an4[q >> 1]);  \
        }                                                                      \
    }                                                                          \
    const float shr = (ar4[0] + ar4[1]) + (ar4[2] + ar4[3]);                   \
    const float shz = (az4[0] + az4[1]) + (az4[2] + az4[3]);                   \
    const float shn = (an4[0] + an4[1]) + (an4[2] + an4[3]);                   \
    float sir = bir, siz = biz, sin_ = bin;                                    \
    _Pragma("unroll") for (int q = 0; q < 8; q++) {                            \
        Q wr, wz, wn;                                                          \
        wr.u = swi[q * 64 + lane];                                             \
        wz.u = swi[512 + q * 64 + lane];                                       \
        wn.u = swi[1024 + q * 64 + lane];                                      \
        _Pragma("unroll") for (int p = 0; p < 4; p++) {                        \
            sir  = fdot2f(wr.h[p], xq[q].h[p], sir);                           \
            siz  = fdot2f(wz.h[p], xq[q].h[p], siz);                           \
            sin_ = fdot2f(wn.h[p], xq[q].h[p], sin_);                          \
        }                                                                      \
    }                                                                          \
    const int kn = __builtin_amdgcn_readfirstlane(ctx[bt0 + tn]);              \
    const unsigned char mn = maskb[(size_t)(bt0 + tn) << mshift];              \
    const float bhr_n = b_hr[kn * H_ + lane];                                  \
    const float bhz_n = b_hz[kn * H_ + lane];                                  \
    const float bhn_n = b_hn[kn * H_ + lane];                                  \
    { const uint4* wp = sw + kn * 1536 + lane;                                 \
      _Pragma("unroll") for (int q = 0; q < 8; q++) {                          \
        WNXT[q].u      = wp[q * 64];                                           \
        WNXT[8 + q].u  = wp[512 + q * 64];                                     \
        WNXT[16 + q].u = wp[1024 + q * 64];                                    \
      } }                                                                      \
    const float arv = sir + shr + bhr_c;                                       \
    const float azv = siz + shz + bhz_c;                                       \
    const float rr  = 1.0f / (1.0f + __expf(-arv));                            \
    const float zz  = 1.0f / (1.0f + __expf(-azv));                            \
    const float aa  = sin_ + rr * (shn + bhn_c);                               \
    const float nn2 = 2.0f / (1.0f + __expf(-2.0f * aa)) - 1.0f;               \
    float hnew = nn2 + zz * (hreg - nn2);                                      \
    hnew = (mc > 0.5f) ? hnew : hreg;                                          \
    hreg = hnew;                                                               \
    { __half* hb = hsc + ((BUF) << 6);                                         \
      hb[lane] = __float2half(hnew);                                           \
      __builtin_amdgcn_wave_barrier();                                         \
      const uint4* hp = (const uint4*)hb;                                      \
      _Pragma("unroll") for (int q = 0; q < 8; q++) hq[q].u = hp[q];           \
      __builtin_amdgcn_wave_barrier(); }                                       \
    { float l0 = hnew * wo0, l1 = hnew * wo1;                                  \
      _Pragma("unroll") for (int m = 32; m >= 1; m >>= 1) {                    \
          l0 += __shfl_xor(l0, m, 64);                                         \
          l1 += __shfl_xor(l1, m, 64);                                         \
      }                                                                        \
      if (lane == 0) *(float2*)(outp + tt * 2) = make_float2(l0 + wob0, l1 + wob1); } \
    bhr_c = bhr_n; bhz_c = bhz_n; bhn_c = bhn_n;                               \
    mc = mn ? 1.0f : 0.0f;                                                     \
}

__global__ __launch_bounds__(128, 1)
void gru_seq6(const __half* __restrict__ xh16, const int* __restrict__ ctx,
              const unsigned char* __restrict__ maskb, const int* __restrict__ flagp,
              const __half* __restrict__ wht,
              const float* __restrict__ b_ir, const float* __restrict__ b_iz,
              const float* __restrict__ b_in, const float* __restrict__ b_hr,
              const float* __restrict__ b_hz, const float* __restrict__ b_hn,
              const float* __restrict__ Wo_w, const float* __restrict__ Wo_b,
              float* __restrict__ out) {
    extern __shared__ __align__(16) char smem[];
    uint4* sw  = (uint4*)smem;          // Wh image (6144 u4)
    uint4* swi = sw + 6144;             // Wi image (1536 u4)

    const int tid  = threadIdx.x;
    const int lane = tid & 63;
    const int wv   = tid >> 6;          // 0,1
    const int b    = blockIdx.x * 2 + wv;

    {
        const uint4* gsrc = (const uint4*)wht;
#pragma unroll 1
        for (int i = tid; i < STAGE_U4; i += 128) sw[i] = gsrc[i];
    }
    __syncthreads();

    const int flag   = *flagp;
    const int mshift = flag ? 0 : 2;
    const int bt0    = b * T_;

    const float bir = b_ir[lane], biz = b_iz[lane], bin = b_in[lane];
    const float wo0 = Wo_w[lane], wo1 = Wo_w[64 + lane];
    const float wob0 = Wo_b[0], wob1 = Wo_b[1];

    __half* hsc = (__half*)(smem + LDS_HSC_OFF + (wv << 8));
    float*  outp = out + (size_t)b * T_ * 2;

    float hreg = 0.0f;
    Q hq[8];
#pragma unroll
    for (int q = 0; q < 8; q++) hq[q].u = make_uint4(0u, 0u, 0u, 0u);

    Q wA[24], wB[24];
    const int k0 = __builtin_amdgcn_readfirstlane(ctx[bt0]);
    float mc = maskb[(size_t)bt0 << mshift] ? 1.0f : 0.0f;
    float bhr_c = b_hr[k0 * H_ + lane];
    float bhz_c = b_hz[k0 * H_ + lane];
    float bhn_c = b_hn[k0 * H_ + lane];
    {
        const uint4* wp = sw + k0 * 1536 + lane;
#pragma unroll
        for (int q = 0; q < 8; q++) {
            wA[q].u      = wp[q * 64];
            wA[8 + q].u  = wp[512 + q * 64];
            wA[16 + q].u = wp[1024 + q * 64];
        }
    }

#pragma unroll 1
    for (int t = 0; t < T_; t += 2) {
        STEP(t,     wA, wB, 0)
        STEP(t + 1, wB, wA, 1)
    }
}

extern "C" void kernel_launch(void* const* d_in, const int* in_sizes, int n_in,
                              void* d_out, int out_size, void* d_ws, size_t ws_size,
                              hipStream_t stream) {
    const float* x    = (const float*)d_in[0];
    const int*   ctx  = (const int*)d_in[1];
    const void*  mask = d_in[2];
    const float* W_ir = (const float*)d_in[3];
    const float* W_iz = (const float*)d_in[4];
    const float* W_in = (const float*)d_in[5];
    const float* bir  = (const float*)d_in[6];
    const float* biz  = (const float*)d_in[7];
    const float* bin  = (const float*)d_in[8];
    const float* W_hr = (const float*)d_in[9];
    const float* W_hz = (const float*)d_in[10];
    const float* W_hn = (const float*)d_in[11];
    const float* bhr  = (const float*)d_in[12];
    const float* bhz  = (const float*)d_in[13];
    const float* bhn  = (const float*)d_in[14];
    const float* Wo_w = (const float*)d_in[15];
    const float* Wo_b = (const float*)d_in[16];

    char* ws = (char*)d_ws;
    __half* wht  = (__half*)ws;
    __half* wit  = (__half*)(ws + WS_WIT_OFF);
    int*    flag = (int*)(ws + WS_FLAG_OFF);

    detect_mask_kernel<<<1, 256, 0, stream>>>((const unsigned char*)mask, flag);
    convert_weights_kernel<<<192, 256, 0, stream>>>(W_hr, W_hz, W_hn, W_ir, W_iz, W_in,
                                                    wht, wit);

    if (ws_size >= (size_t)WS_NEED_FAST) {
        // fast path: pipelined iproj + asm-pinned-prefetch sequence + deferred logits
        float*  iproj = (float*)(ws + WS_IPJ_OFF);
        __half* hh    = (__half*)(ws + WS_HH_OFF);
        iproj_kernel<<<B_ * T_ / 32, 256, 0, stream>>>(x, wit, bir, biz, bin, iproj);
        (void)hipFuncSetAttribute((const void*)gru_seq12,
                                  hipFuncAttributeMaxDynamicSharedMemorySize, LDS12_TOTAL);
        gru_seq12<<<B_ / 2, 128, LDS12_TOTAL, stream>>>(
            iproj, ctx, (const unsigned char*)mask, flag, wht, bhr, bhz, bhn, hh);
        logits_kernel<<<B_ * T_ / 256, 256, 0, stream>>>(hh, Wo_w, Wo_b, (float*)d_out);
    } else {
        // fallback: previous verified pipeline
        __half* xh16 = (__half*)(ws + WS_XH_OFF);
        convert_x_kernel<<<8192, 256, 0, stream>>>(x, xh16);
        (void)hipFuncSetAttribute((const void*)gru_seq6,
                                  hipFuncAttributeMaxDynamicSharedMemorySize, LDS_TOTAL);
        gru_seq6<<<B_ / 2, 128, LDS_TOTAL, stream>>>(
            xh16, ctx, (const unsigned char*)mask, flag, wht,
            bir, biz, bin, bhr, bhz, bhn, Wo_w, Wo_b, (float*)d_out);
    }
}